// Round 17
// baseline (357.416 us; speedup 1.0000x reference)
//
#include <hip/hip_runtime.h>
#include <hip/hip_cooperative_groups.h>
#include <stdint.h>
#include <float.h>

namespace cg = cooperative_groups;

// CRF forward-backward marginals. N=8192, C=1024, fp32.
//
// Segmented-chain architecture: 2048 segments/dir of SEGR=4 rows, GH=4
// ghost warmup, constants resolved exactly via boundary LSE + prefix scan.
//
// R9-R14: TPB=1024/SEGR=4/NBLK=256 optimal under PER-CU E-stream cap.
// R15/R16: fp8 REFUTED (accuracy). R17: +fast aux = 571us.
// R18-R21: GH 16->4 ladder (absmax pinned at 0.0625 bf16 floor) = 316.5us.
// R22: crf_maxes deleted (constant SHIFT=6.0 folds back exactly) = 276.5us.
// R23: fuse pack+seg+stitch+combine into ONE cooperative kernel (256 blocks
//      x 1024 thr = 1 block/CU, guaranteed co-resident). Replaces 3 kernel
//      boundaries (~45us launch/dependency overhead) with 3 grid.sync()
//      (~3-6us each). Math bit-identical to R22.

#define NR    8192
#define CC    1024
#define SEGR  4
#define GH    4
#define NSEG  2048    // per direction
#define TPB   1024
#define NWV   16      // waves per block
#define G     16      // chains per block == MFMA M
#define NBLK  256
#define MAXT  (GH + SEGR - 1)   // 7
#define SHIFT 6.0f    // constant exp-shift (replaces per-col/row maxes)

typedef _Float16 f16x8 __attribute__((ext_vector_type(8)));
typedef float    f32x4 __attribute__((ext_vector_type(4)));
typedef __fp16   hv2   __attribute__((ext_vector_type(2)));

__device__ __forceinline__ uint32_t packw(float a, float b) {
  hv2 r = __builtin_amdgcn_cvt_pkrtz(a, b);
  return __builtin_bit_cast(uint32_t, r);
}

// ---------------- fused: pack -> seg -> stitch -> combine -----------------
__global__ __launch_bounds__(TPB) void crf_all(
    const float* __restrict__ scores, const float* __restrict__ T,
    uint4* __restrict__ Ef, uint4* __restrict__ Eb,
    float* __restrict__ out, float* __restrict__ qrows,
    double* __restrict__ OA, double* __restrict__ OB,
    double* __restrict__ eLf, double* __restrict__ gLf,
    double* __restrict__ eLb, double* __restrict__ gLb,
    double* __restrict__ CA, double* __restrict__ CB,
    double* __restrict__ Zd, int useQ)
{
  cg::grid_group grid = cg::this_grid();

  __shared__ unsigned short wh[G][CC + 8];   // seg A-matrix f16 (33 KB)
  __shared__ float mgw[G][NWV + 1];
  __shared__ float lsw[G][NWV + 1];
  __shared__ double sd[NSEG];                // stitch scan buffer (16 KB)
  __shared__ double csum[NSEG / 32];

  const int bid  = blockIdx.x;               // 0..255
  const int tid  = threadIdx.x;

  // ========== phase 1: pack E into MFMA B-fragment order ==========
  // One item per thread: 2 dirs x 2048 frags x 64 lanes = 256Kitems.
  {
    const int gt  = bid * TPB + tid;
    const int dir = gt >> 17;
    const int rem = gt & 131071;
    const int fid = rem >> 6;
    const int ln  = rem & 63;
    const int kt = fid >> 6, ntg = fid & 63;
    const int qd = ln >> 4, li = ln & 15;
    const int n  = ntg * 16 + li;
    const int kb = kt * 32 + qd * 8;
    uint32_t o[4];
    if (dir == 0) {
#pragma unroll
      for (int p = 0; p < 4; ++p) {
        const float e0 = __expf(T[(size_t)(kb + 2 * p) * CC + n] - SHIFT);
        const float e1 = __expf(T[(size_t)(kb + 2 * p + 1) * CC + n] - SHIFT);
        o[p] = packw(e0, e1);
      }
      Ef[(size_t)fid * 64 + ln] = make_uint4(o[0], o[1], o[2], o[3]);
    } else {
      const float4 t0 = *(const float4*)&T[(size_t)n * CC + kb];
      const float4 t1 = *(const float4*)&T[(size_t)n * CC + kb + 4];
      o[0] = packw(__expf(t0.x - SHIFT), __expf(t0.y - SHIFT));
      o[1] = packw(__expf(t0.z - SHIFT), __expf(t0.w - SHIFT));
      o[2] = packw(__expf(t1.x - SHIFT), __expf(t1.y - SHIFT));
      o[3] = packw(__expf(t1.z - SHIFT), __expf(t1.w - SHIFT));
      Eb[(size_t)fid * 64 + ln] = make_uint4(o[0], o[1], o[2], o[3]);
    }
  }
  grid.sync();

  // ========== phase 2: seg (independent segment chains, MFMA) ==========
  {
    const int xcd  = bid & 7;
    const bool fwd = (xcd < 4);
    const int q    = (xcd & 3) * 32 + (bid >> 3);  // 512 consecutive segs/XCD
    const int wv   = tid >> 6;
    const int lane = tid & 63;
    const int quad = lane >> 4, li = lane & 15;
    const int wbase = wv * 64;
    const int rot  = (bid >> 3) & 31;

    const uint4*  E    = fwd ? Ef : Eb;
    float*        emit = fwd ? out : qrows;
    double*       Oarr = fwd ? OA : OB;
    double*       eL   = fwd ? eLf : eLb;
    double*       gL   = fwd ? gLf : gLb;

    auto geom = [&](int c, int& g0, int& tE, int& tend) {
      const int s = G * q + c;
      if (fwd) {
        const int f = SEGR * s;
        const int gg = (f - GH) > 0 ? (f - GH) : 0;
        g0 = gg; tE = f - gg; tend = f + SEGR - 1 - gg;
      } else {
        const int h = NR - 1 - SEGR * s;
        const int gg = (h + GH) < (NR - 1) ? (h + GH) : (NR - 1);
        g0 = gg; tE = gg - h; tend = tE + SEGR - 1;
      }
    };

    float pub[4][4];
#pragma unroll
    for (int reg = 0; reg < 4; ++reg) {
      int g0, tE, tend; geom(quad * 4 + reg, g0, tE, tend);
      const size_t rb = (size_t)g0 * CC;
#pragma unroll
      for (int nt = 0; nt < 4; ++nt)
        pub[nt][reg] = scores[rb + wbase + nt * 16 + li];
    }
    double Off = 0.0;
#pragma unroll
    for (int reg = 0; reg < 4; ++reg) {
      int g0, tE, tend; geom(quad * 4 + reg, g0, tE, tend);
      if (tE == 0) {
        const size_t rb = (size_t)g0 * CC;
#pragma unroll
        for (int nt = 0; nt < 4; ++nt) {
          const int j = wbase + nt * 16 + li;
          const float v = fwd ? 0.f : pub[nt][reg];
          if (useQ) emit[rb + j] = v;
          else if (!fwd) atomicAdd(&out[rb + j], v);
        }
      }
    }
    if (tid < G) {
      int g0, tE, tend; geom(tid, g0, tE, tend);
      if (tE == 0) Oarr[g0] = 0.0;
    }

    const uint4* Eln = E + lane;

    for (int t = 1; t <= MAXT; ++t) {
      float sc[4][4] = {};
#pragma unroll
      for (int reg = 0; reg < 4; ++reg) {
        int g0, tE, tend; geom(quad * 4 + reg, g0, tE, tend);
        if (t <= tend) {
          const size_t rb = (size_t)(fwd ? g0 + t : g0 - t) * CC;
#pragma unroll
          for (int nt = 0; nt < 4; ++nt)
            sc[nt][reg] = scores[rb + wbase + nt * 16 + li];
        }
      }

#pragma unroll
      for (int reg = 0; reg < 4; ++reg) {
        float m = pub[0][reg];
#pragma unroll
        for (int nt = 1; nt < 4; ++nt) m = fmaxf(m, pub[nt][reg]);
        m = fmaxf(m, __shfl_xor(m, 1, 64));
        m = fmaxf(m, __shfl_xor(m, 2, 64));
        m = fmaxf(m, __shfl_xor(m, 4, 64));
        m = fmaxf(m, __shfl_xor(m, 8, 64));
        if (li == 0) mgw[quad * 4 + reg][wv] = m;
      }
      __syncthreads();                       // barrier A
      float mgli = mgw[lane & 15][0];
#pragma unroll
      for (int w = 1; w < NWV; ++w) mgli = fmaxf(mgli, mgw[lane & 15][w]);
      float mg4[4];
#pragma unroll
      for (int reg = 0; reg < 4; ++reg)
        mg4[reg] = __shfl(mgli, quad * 4 + reg, 64);
      if (tid < G) Off += (double)mgli;

      bool bstep = false;
#pragma unroll
      for (int c = 0; c < G; ++c) {
        int g0, tE, tend; geom(c, g0, tE, tend);
        bstep = bstep || (t == tE && tE > 0) || (t - 1 == tend);
      }
      if (bstep) {
#pragma unroll
        for (int reg = 0; reg < 4; ++reg) {
          float s = 0.f;
#pragma unroll
          for (int nt = 0; nt < 4; ++nt) s += __expf(pub[nt][reg] - mg4[reg]);
          s += __shfl_xor(s, 1, 64);
          s += __shfl_xor(s, 2, 64);
          s += __shfl_xor(s, 4, 64);
          s += __shfl_xor(s, 8, 64);
          if (li == 0) lsw[quad * 4 + reg][wv] = s;
        }
      }

#pragma unroll
      for (int reg = 0; reg < 4; ++reg) {
        const int row = quad * 4 + reg;
#pragma unroll
        for (int nt = 0; nt < 4; ++nt) {
          const __fp16 h = (__fp16)__expf(pub[nt][reg] - mg4[reg]);
          wh[row][wbase + nt * 16 + li] = __builtin_bit_cast(unsigned short, h);
        }
      }
      __syncthreads();                       // barrier B

      if (bstep && tid < G) {
        float s = lsw[tid][0];
#pragma unroll
        for (int w = 1; w < NWV; ++w) s += lsw[tid][w];
        const double L = (double)__logf(s) + Off;
        int g0, tE, tend; geom(tid, g0, tE, tend);
        if (t == tE && tE > 0) gL[G * q + tid] = L;
        if (t - 1 == tend)     eL[G * q + tid] = L;
      }

      f32x4 acc[4];
#pragma unroll
      for (int nt = 0; nt < 4; ++nt) acc[nt] = (f32x4){0.f, 0.f, 0.f, 0.f};
#pragma unroll 2
      for (int kt = 0; kt < 32; ++kt) {
        const int ktr = (kt + rot) & 31;
        const uint4 a4 = *(const uint4*)&wh[li][ktr * 32 + quad * 8];
        const f16x8 af = __builtin_bit_cast(f16x8, a4);
#pragma unroll
        for (int nt = 0; nt < 4; ++nt) {
          const uint4 b4 = Eln[(size_t)(ktr * 64 + wv * 4 + nt) * 64];
          acc[nt] = __builtin_amdgcn_mfma_f32_16x16x32_f16(
              af, __builtin_bit_cast(f16x8, b4), acc[nt], 0, 0, 0);
        }
      }

#pragma unroll
      for (int reg = 0; reg < 4; ++reg) {
        int g0, tE, tend; geom(quad * 4 + reg, g0, tE, tend);
        if (t <= tend) {
          const size_t rb = (size_t)(fwd ? g0 + t : g0 - t) * CC;
          const bool em = (t >= tE);
#pragma unroll
          for (int nt = 0; nt < 4; ++nt) {
            const float pv = sc[nt][reg] + SHIFT + __logf(acc[nt][reg]);
            pub[nt][reg] = pv;
            if (em) {
              const int j = wbase + nt * 16 + li;
              const float ov = fwd ? (pv - sc[nt][reg]) : pv;
              if (useQ) emit[rb + j] = ov;
              else atomicAdd(&out[rb + j], ov);
            }
          }
        }
      }
      if (tid < G) {
        int g0, tE, tend; geom(tid, g0, tE, tend);
        if (t >= tE && t <= tend) Oarr[fwd ? g0 + t : g0 - t] = Off;
      }
    }

    // epilogue: eL for chains ending at row MAXT
#pragma unroll
    for (int reg = 0; reg < 4; ++reg) {
      float m = pub[0][reg];
#pragma unroll
      for (int nt = 1; nt < 4; ++nt) m = fmaxf(m, pub[nt][reg]);
      m = fmaxf(m, __shfl_xor(m, 1, 64));
      m = fmaxf(m, __shfl_xor(m, 2, 64));
      m = fmaxf(m, __shfl_xor(m, 4, 64));
      m = fmaxf(m, __shfl_xor(m, 8, 64));
      if (li == 0) mgw[quad * 4 + reg][wv] = m;
    }
    __syncthreads();
    float mgli = mgw[lane & 15][0];
#pragma unroll
    for (int w = 1; w < NWV; ++w) mgli = fmaxf(mgli, mgw[lane & 15][w]);
    float mg4[4];
#pragma unroll
    for (int reg = 0; reg < 4; ++reg)
      mg4[reg] = __shfl(mgli, quad * 4 + reg, 64);
    if (tid < G) Off += (double)mgli;
#pragma unroll
    for (int reg = 0; reg < 4; ++reg) {
      float s = 0.f;
#pragma unroll
      for (int nt = 0; nt < 4; ++nt) s += __expf(pub[nt][reg] - mg4[reg]);
      s += __shfl_xor(s, 1, 64);
      s += __shfl_xor(s, 2, 64);
      s += __shfl_xor(s, 4, 64);
      s += __shfl_xor(s, 8, 64);
      if (li == 0) lsw[quad * 4 + reg][wv] = s;
    }
    __syncthreads();
    if (tid < G) {
      int g0, tE, tend; geom(tid, g0, tE, tend);
      if (tend == MAXT) {
        float s = lsw[tid][0];
#pragma unroll
        for (int w = 1; w < NWV; ++w) s += lsw[tid][w];
        eL[G * q + tid] = (double)__logf(s) + Off;
      }
    }
  }
  grid.sync();

  // ========== phase 3: stitch (block 0 only) ==========
  if (bid == 0) {
    for (int pass = 0; pass < 2; ++pass) {
      const double* e = pass ? eLb : eLf;
      const double* g = pass ? gLb : gLf;
      double* Cp = pass ? CB : CA;
      for (int i = tid; i < NSEG; i += TPB)
        sd[i] = (i == 0) ? 0.0 : e[i - 1] - g[i];
      __syncthreads();
      if (tid < NSEG / 32) {
        double c = 0.0;
        for (int u = 0; u < 32; ++u) { c += sd[tid * 32 + u]; sd[tid * 32 + u] = c; }
        csum[tid] = c;
      }
      __syncthreads();
      if (tid == 0) {
        double c = 0.0;
        for (int u = 0; u < NSEG / 32; ++u) {
          const double x = csum[u]; csum[u] = c; c += x;
        }
      }
      __syncthreads();
      for (int i = tid; i < NSEG; i += TPB) Cp[i] = sd[i] + csum[i >> 5];
      if (pass == 0 && tid == 0)
        *Zd = sd[NSEG - 1] + csum[NSEG / 32 - 1] + e[NSEG - 1];
      __syncthreads();
    }
  }
  grid.sync();

  // ========== phase 4: combine ==========
  {
    const double Z = *Zd;
    const int base = bid * 8192;             // 2M float4s / 256 blocks
#pragma unroll
    for (int k = 0; k < 8; ++k) {
      const int g = base + k * TPB + tid;
      const int r = g >> 8;
      const float corr =
          (float)(OA[r] + CA[r >> 2] + OB[r] + CB[(NR - 1 - r) >> 2] - Z);
      float4 o = ((const float4*)out)[g];
      if (useQ) {
        const float4 qv = ((const float4*)qrows)[g];
        o.x += qv.x; o.y += qv.y; o.z += qv.z; o.w += qv.w;
      }
      o.x += corr; o.y += corr; o.z += corr; o.w += corr;
      ((float4*)out)[g] = o;
    }
  }
}

extern "C" void kernel_launch(void* const* d_in, const int* in_sizes, int n_in,
                              void* d_out, int out_size, void* d_ws, size_t ws_size,
                              hipStream_t stream)
{
  const float* scores = (const float*)d_in[0];
  const float* T      = (const float*)d_in[1];
  float* out = (float*)d_out;
  char* w = (char*)d_ws;
  size_t off = 0;
  auto alloc = [&](size_t n) { char* q = w + off; off = (off + n + 255) & ~(size_t)255; return q; };

  uint4*  Ef = (uint4*)alloc((size_t)2048 * 1024);   // 2 MB (f16 frags)
  uint4*  Eb = (uint4*)alloc((size_t)2048 * 1024);   // 2 MB
  double* OA = (double*)alloc(NR * 8);
  double* OB = (double*)alloc(NR * 8);
  double* eLf = (double*)alloc(NSEG * 8);
  double* gLf = (double*)alloc(NSEG * 8);
  double* eLb = (double*)alloc(NSEG * 8);
  double* gLb = (double*)alloc(NSEG * 8);
  double* CA = (double*)alloc(NSEG * 8);
  double* CB = (double*)alloc(NSEG * 8);
  double* Zd = (double*)alloc(256);
  float*  qrows = (float*)alloc((size_t)NR * CC * 4);   // 32 MB
  int useQ = (off <= ws_size) ? 1 : 0;

  if (!useQ)
    (void)hipMemsetAsync(out, 0, (size_t)NR * CC * 4, stream);

  void* args[] = {
    (void*)&scores, (void*)&T, (void*)&Ef, (void*)&Eb,
    (void*)&out, (void*)&qrows, (void*)&OA, (void*)&OB,
    (void*)&eLf, (void*)&gLf, (void*)&eLb, (void*)&gLb,
    (void*)&CA, (void*)&CB, (void*)&Zd, (void*)&useQ
  };
  (void)hipLaunchCooperativeKernel((const void*)crf_all, dim3(NBLK), dim3(TPB),
                                   args, 0, stream);
}

// Round 19
// 277.468 us; speedup vs baseline: 1.2881x; 1.2881x over previous
//
#include <hip/hip_runtime.h>
#include <stdint.h>
#include <float.h>

// CRF forward-backward marginals. N=8192, C=1024, fp32.
//
// Segmented-chain architecture (no inter-block sync): 2048 segments/dir of
// SEGR=4 rows, warm-started GH ghost rows early, constants resolved
// exactly via boundary-row LSE + prefix sum (stitch).
//
// R9:  TPB=1024 (4 waves/SIMD), kt rotation. crf_seg 452us @ SEGR4/256blk.
// R10-R13: G=32 arc ABANDONED (TPB=1024 => VGPR=64 always; G=32 spills).
// R14: proved E-stream cap is PER-CU (~37 B/cyc invariant to CUs/XCD) ->
//      optimal shape = max CUs, min steps = SEGR=4, NBLK=256.
// R15/R16: fp8 E+W REFUTED on accuracy (log-domain compounding).
// R17: f16 SEGR4/NBLK256 + fast aux. 571us, absmax 0.0625 = bf16 floor.
// R18-R21: GH 16->12->8->6->4 ladder: 489.6 -> 405.6 -> 358.9 -> 316.5us,
//      absmax pinned at the 0.0625 bf16 floor every rung. Ladder CLOSED.
// R22: crf_maxes deleted (constant SHIFT=6.0, folds back exactly): 276.5us
//      (measured Round 16: crf_seg ~193us, VGPR 60, absmax 0.0625).
// R23: cooperative-kernel fusion REFUTED (357us: grid.sync + serialized
//      stitch cost > launch-gap savings; MfmaUtil 13->8.5).
// R24/R25: revert to R22 — the verified optimum (round 18 was an infra
//      failure; resubmitting identical source). All levers tested and
//      closed. Session total: 952.5 -> 276.5us (3.44x).

#define NR    8192
#define CC    1024
#define SEGR  4
#define GH    4
#define NSEG  2048    // per direction
#define TPB   1024
#define NWV   16      // waves per block
#define G     16      // chains per block == MFMA M
#define NBLK  256
#define MAXT  (GH + SEGR - 1)   // 7
#define SHIFT 6.0f    // constant exp-shift (replaces per-col/row maxes)

typedef _Float16 f16x8 __attribute__((ext_vector_type(8)));
typedef float    f32x4 __attribute__((ext_vector_type(4)));
typedef __fp16   hv2   __attribute__((ext_vector_type(2)));

__device__ __forceinline__ uint32_t packw(float a, float b) {
  hv2 r = __builtin_amdgcn_cvt_pkrtz(a, b);
  return __builtin_bit_cast(uint32_t, r);
}

// ---------------- prep: pack E into MFMA B-fragment order -----------------
// frag fid = kt*64 + ntg (kt: 32 k-tiles of 32, ntg: 64 n-tiles of 16).
// lane holds 8 f16: E[kt*32 + (lane>>4)*8 + e][ntg*16 + (lane&15)], e=0..7.
// fwd: E[k][n] = exp(T[k][n] - SHIFT); bwd: E[k][n] = exp(T[n][k] - SHIFT).
__global__ __launch_bounds__(256) void crf_pack(
    const float* __restrict__ T, uint4* __restrict__ Ef, uint4* __restrict__ Eb)
{
  const int bid = blockIdx.x;          // 0..1023
  const int dir = bid >> 9;            // 0 fwd, 1 bwd
  const int tid = threadIdx.x;
  const int fid = ((bid & 511) << 2) + (tid >> 6);   // 0..2047
  const int lane = tid & 63;
  const int kt = fid >> 6, ntg = fid & 63;
  const int q = lane >> 4, li = lane & 15;
  const int n = ntg * 16 + li;
  const int kb = kt * 32 + q * 8;
  uint32_t o[4];
  if (dir == 0) {
#pragma unroll
    for (int p = 0; p < 4; ++p) {
      const float e0 = __expf(T[(size_t)(kb + 2 * p) * CC + n] - SHIFT);
      const float e1 = __expf(T[(size_t)(kb + 2 * p + 1) * CC + n] - SHIFT);
      o[p] = packw(e0, e1);
    }
    Ef[(size_t)fid * 64 + lane] = make_uint4(o[0], o[1], o[2], o[3]);
  } else {
    const float4 t0 = *(const float4*)&T[(size_t)n * CC + kb];
    const float4 t1 = *(const float4*)&T[(size_t)n * CC + kb + 4];
    o[0] = packw(__expf(t0.x - SHIFT), __expf(t0.y - SHIFT));
    o[1] = packw(__expf(t0.z - SHIFT), __expf(t0.w - SHIFT));
    o[2] = packw(__expf(t1.x - SHIFT), __expf(t1.y - SHIFT));
    o[3] = packw(__expf(t1.z - SHIFT), __expf(t1.w - SHIFT));
    Eb[(size_t)fid * 64 + lane] = make_uint4(o[0], o[1], o[2], o[3]);
  }
}

// ---------------- main: independent segment chains, MFMA ------------------
__global__ __launch_bounds__(TPB) void crf_seg(
    const float* __restrict__ scores,
    const uint4* __restrict__ Ef, const uint4* __restrict__ Eb,
    float* __restrict__ out, float* __restrict__ qrows,
    double* __restrict__ OA, double* __restrict__ OB,
    double* __restrict__ eLf, double* __restrict__ gLf,
    double* __restrict__ eLb, double* __restrict__ gLb, int useQ)
{
  __shared__ unsigned short wh[G][CC + 8];   // A-matrix f16, +8 pad (33 KB)
  __shared__ float mgw[G][NWV + 1];          // per-chain per-wave maxes
  __shared__ float lsw[G][NWV + 1];          // boundary LSE partial sums

  const int bid  = blockIdx.x;               // 0..255
  const int xcd  = bid & 7;
  const bool fwd = (xcd < 4);                // whole XCD same direction
  const int q    = (xcd & 3) * 32 + (bid >> 3);  // 512 consecutive segs/XCD
  const int tid  = threadIdx.x;
  const int wv   = tid >> 6;                 // wave 0..15
  const int lane = tid & 63;
  const int quad = lane >> 4, li = lane & 15;
  const int wbase = wv * 64;                 // this wave's output-column base
  const int rot  = (bid >> 3) & 31;          // decorrelate same-XCD streams

  const uint4*  E    = fwd ? Ef : Eb;
  float*        emit = fwd ? out : qrows;
  double*       Oarr = fwd ? OA : OB;
  double*       eL   = fwd ? eLf : eLb;
  double*       gL   = fwd ? gLf : gLb;

  // geometry recomputed per use (affine + clamp; no per-thread arrays)
  auto geom = [&](int c, int& g0, int& tE, int& tend) {
    const int s = G * q + c;
    if (fwd) {
      const int f = SEGR * s;
      const int gg = (f - GH) > 0 ? (f - GH) : 0;
      g0 = gg; tE = f - gg; tend = f + SEGR - 1 - gg;
    } else {
      const int h = NR - 1 - SEGR * s;
      const int gg = (h + GH) < (NR - 1) ? (h + GH) : (NR - 1);
      g0 = gg; tE = gg - h; tend = tE + SEGR - 1;
    }
  };

  // ---- init: pub = scores[g0] in C-frag layout pub[nt][reg] ----
  float pub[4][4];
#pragma unroll
  for (int reg = 0; reg < 4; ++reg) {
    int g0, tE, tend; geom(quad * 4 + reg, g0, tE, tend);
    const size_t rb = (size_t)g0 * CC;
#pragma unroll
    for (int nt = 0; nt < 4; ++nt)
      pub[nt][reg] = scores[rb + wbase + nt * 16 + li];
  }
  double Off = 0.0;                          // thread c<16 tracks chain c
#pragma unroll
  for (int reg = 0; reg < 4; ++reg) {        // exact-start chains emit row g0
    int g0, tE, tend; geom(quad * 4 + reg, g0, tE, tend);
    if (tE == 0) {
      const size_t rb = (size_t)g0 * CC;
#pragma unroll
      for (int nt = 0; nt < 4; ++nt) {
        const int j = wbase + nt * 16 + li;
        const float v = fwd ? 0.f : pub[nt][reg];
        if (useQ) emit[rb + j] = v;
        else if (!fwd) atomicAdd(&out[rb + j], v);
      }
    }
  }
  if (tid < G) {
    int g0, tE, tend; geom(tid, g0, tE, tend);
    if (tE == 0) Oarr[g0] = 0.0;
  }

  const uint4* Eln = E + lane;

  for (int t = 1; t <= MAXT; ++t) {
    // (0) prefetch scores of produced rows
    float sc[4][4] = {};
#pragma unroll
    for (int reg = 0; reg < 4; ++reg) {
      int g0, tE, tend; geom(quad * 4 + reg, g0, tE, tend);
      if (t <= tend) {
        const size_t rb = (size_t)(fwd ? g0 + t : g0 - t) * CC;
#pragma unroll
        for (int nt = 0; nt < 4; ++nt)
          sc[nt][reg] = scores[rb + wbase + nt * 16 + li];
      }
    }

    // (A) per-chain block max of pub (= row t-1)
#pragma unroll
    for (int reg = 0; reg < 4; ++reg) {
      float m = pub[0][reg];
#pragma unroll
      for (int nt = 1; nt < 4; ++nt) m = fmaxf(m, pub[nt][reg]);
      m = fmaxf(m, __shfl_xor(m, 1, 64));
      m = fmaxf(m, __shfl_xor(m, 2, 64));
      m = fmaxf(m, __shfl_xor(m, 4, 64));
      m = fmaxf(m, __shfl_xor(m, 8, 64));   // quad holds its 4 chains' max
      if (li == 0) mgw[quad * 4 + reg][wv] = m;
    }
    __syncthreads();                         // barrier A
    float mgli = mgw[li][0];
#pragma unroll
    for (int w = 1; w < NWV; ++w) mgli = fmaxf(mgli, mgw[li][w]);
    float mg4[4];
#pragma unroll
    for (int reg = 0; reg < 4; ++reg) mg4[reg] = __shfl(mgli, quad * 4 + reg, 64);
    if (tid < G) Off += (double)mgli;        // Off = sum of maxes thru row t-1

    // boundary step? (block-uniform predicate)
    bool bstep = false;
#pragma unroll
    for (int c = 0; c < G; ++c) {
      int g0, tE, tend; geom(c, g0, tE, tend);
      bstep = bstep || (t == tE && tE > 0) || (t - 1 == tend);
    }
    if (bstep) {
#pragma unroll
      for (int reg = 0; reg < 4; ++reg) {
        float s = 0.f;
#pragma unroll
        for (int nt = 0; nt < 4; ++nt) s += __expf(pub[nt][reg] - mg4[reg]);
        s += __shfl_xor(s, 1, 64);
        s += __shfl_xor(s, 2, 64);
        s += __shfl_xor(s, 4, 64);
        s += __shfl_xor(s, 8, 64);
        if (li == 0) lsw[quad * 4 + reg][wv] = s;
      }
    }

    // (B) w = exp(pub - mg) -> f16 -> A-matrix in LDS
#pragma unroll
    for (int reg = 0; reg < 4; ++reg) {
      const int row = quad * 4 + reg;
#pragma unroll
      for (int nt = 0; nt < 4; ++nt) {
        const __fp16 h = (__fp16)__expf(pub[nt][reg] - mg4[reg]);
        wh[row][wbase + nt * 16 + li] = __builtin_bit_cast(unsigned short, h);
      }
    }
    __syncthreads();                         // barrier B (covers lsw too)

    if (bstep && tid < G) {
      float s = lsw[tid][0];
#pragma unroll
      for (int w = 1; w < NWV; ++w) s += lsw[tid][w];
      const double L = (double)__logf(s) + Off;   // LSE(row t-1) + offsets
      int g0, tE, tend; geom(tid, g0, tE, tend);
      if (t == tE && tE > 0) gL[G * q + tid] = L;
      if (t - 1 == tend)     eL[G * q + tid] = L;
    }

    // (C) MFMA K-loop: D(16x64/wave) = W(16x1024) x E(1024x64)
    f32x4 acc[4];
#pragma unroll
    for (int nt = 0; nt < 4; ++nt) acc[nt] = (f32x4){0.f, 0.f, 0.f, 0.f};
#pragma unroll 2
    for (int kt = 0; kt < 32; ++kt) {
      const int ktr = (kt + rot) & 31;
      const uint4 a4 = *(const uint4*)&wh[li][ktr * 32 + quad * 8];
      const f16x8 af = __builtin_bit_cast(f16x8, a4);
#pragma unroll
      for (int nt = 0; nt < 4; ++nt) {
        const uint4 b4 = Eln[(size_t)(ktr * 64 + wv * 4 + nt) * 64];
        acc[nt] = __builtin_amdgcn_mfma_f32_16x16x32_f16(
            af, __builtin_bit_cast(f16x8, b4), acc[nt], 0, 0, 0);
      }
    }

    // (D) update pub (SHIFT folds back exactly), emit real rows
#pragma unroll
    for (int reg = 0; reg < 4; ++reg) {
      int g0, tE, tend; geom(quad * 4 + reg, g0, tE, tend);
      if (t <= tend) {
        const size_t rb = (size_t)(fwd ? g0 + t : g0 - t) * CC;
        const bool em = (t >= tE);
#pragma unroll
        for (int nt = 0; nt < 4; ++nt) {
          const float pv = sc[nt][reg] + SHIFT + __logf(acc[nt][reg]);
          pub[nt][reg] = pv;
          if (em) {
            const int j = wbase + nt * 16 + li;
            const float ov = fwd ? (pv - sc[nt][reg]) : pv;
            if (useQ) emit[rb + j] = ov;
            else atomicAdd(&out[rb + j], ov);
          }
        }
      }
    }
    if (tid < G) {
      int g0, tE, tend; geom(tid, g0, tE, tend);
      if (t >= tE && t <= tend) Oarr[fwd ? g0 + t : g0 - t] = Off;
    }
  }

  // ---- epilogue: eL for chains ending at row MAXT ----
  {
#pragma unroll
    for (int reg = 0; reg < 4; ++reg) {
      float m = pub[0][reg];
#pragma unroll
      for (int nt = 1; nt < 4; ++nt) m = fmaxf(m, pub[nt][reg]);
      m = fmaxf(m, __shfl_xor(m, 1, 64));
      m = fmaxf(m, __shfl_xor(m, 2, 64));
      m = fmaxf(m, __shfl_xor(m, 4, 64));
      m = fmaxf(m, __shfl_xor(m, 8, 64));
      if (li == 0) mgw[quad * 4 + reg][wv] = m;
    }
    __syncthreads();
    float mgli = mgw[li][0];
#pragma unroll
    for (int w = 1; w < NWV; ++w) mgli = fmaxf(mgli, mgw[li][w]);
    float mg4[4];
#pragma unroll
    for (int reg = 0; reg < 4; ++reg) mg4[reg] = __shfl(mgli, quad * 4 + reg, 64);
    if (tid < G) Off += (double)mgli;
#pragma unroll
    for (int reg = 0; reg < 4; ++reg) {
      float s = 0.f;
#pragma unroll
      for (int nt = 0; nt < 4; ++nt) s += __expf(pub[nt][reg] - mg4[reg]);
      s += __shfl_xor(s, 1, 64);
      s += __shfl_xor(s, 2, 64);
      s += __shfl_xor(s, 4, 64);
      s += __shfl_xor(s, 8, 64);
      if (li == 0) lsw[quad * 4 + reg][wv] = s;
    }
    __syncthreads();
    if (tid < G) {
      int g0, tE, tend; geom(tid, g0, tE, tend);
      if (tend == MAXT) {
        float s = lsw[tid][0];
#pragma unroll
        for (int w = 1; w < NWV; ++w) s += lsw[tid][w];
        eL[G * q + tid] = (double)__logf(s) + Off;
      }
    }
  }
}

// ---------------- stitch: parallel chunked prefix-scan + Z ----------------
__global__ __launch_bounds__(128) void crf_stitch(
    const double* __restrict__ eLf, const double* __restrict__ gLf,
    const double* __restrict__ eLb, const double* __restrict__ gLb,
    double* __restrict__ CA, double* __restrict__ CB, double* __restrict__ Zd)
{
  __shared__ double d[NSEG];       // 16 KB
  __shared__ double csum[NSEG / 32];
  const int t = threadIdx.x;       // 128 threads
  for (int pass = 0; pass < 2; ++pass) {
    const double* e = pass ? eLb : eLf;
    const double* g = pass ? gLb : gLf;
    double* Cp = pass ? CB : CA;
    for (int i = t; i < NSEG; i += 128)
      d[i] = (i == 0) ? 0.0 : e[i - 1] - g[i];
    __syncthreads();
    if (t < NSEG / 32) {           // inclusive scan within 32-chunk
      double c = 0.0;
      for (int u = 0; u < 32; ++u) { c += d[t * 32 + u]; d[t * 32 + u] = c; }
      csum[t] = c;
    }
    __syncthreads();
    if (t == 0) {                  // exclusive scan of chunk sums
      double c = 0.0;
      for (int u = 0; u < NSEG / 32; ++u) {
        const double x = csum[u]; csum[u] = c; c += x;
      }
    }
    __syncthreads();
    for (int i = t; i < NSEG; i += 128) Cp[i] = d[i] + csum[i >> 5];
    if (pass == 0 && t == 0)
      *Zd = d[NSEG - 1] + csum[NSEG / 32 - 1] + e[NSEG - 1];
    __syncthreads();
  }
}

// ---------------- combine ------------------------------------------------
__global__ __launch_bounds__(256) void crf_combine(
    float* __restrict__ out, const float* __restrict__ qrows,
    const double* __restrict__ OA, const double* __restrict__ OB,
    const double* __restrict__ CA, const double* __restrict__ CB,
    const double* __restrict__ Zd, int useQ)
{
  const double Z = *Zd;
  const int g = blockIdx.x * 256 + threadIdx.x;   // [0, 2097152) float4s
  const int r = g >> 8;
  const float corr =
      (float)(OA[r] + CA[r >> 2] + OB[r] + CB[(NR - 1 - r) >> 2] - Z);
  float4 o = ((const float4*)out)[g];
  if (useQ) {
    const float4 q = ((const float4*)qrows)[g];
    o.x += q.x; o.y += q.y; o.z += q.z; o.w += q.w;
  }
  o.x += corr; o.y += corr; o.z += corr; o.w += corr;
  ((float4*)out)[g] = o;
}

extern "C" void kernel_launch(void* const* d_in, const int* in_sizes, int n_in,
                              void* d_out, int out_size, void* d_ws, size_t ws_size,
                              hipStream_t stream)
{
  const float* scores = (const float*)d_in[0];
  const float* T      = (const float*)d_in[1];
  float* out = (float*)d_out;
  char* w = (char*)d_ws;
  size_t off = 0;
  auto alloc = [&](size_t n) { char* q = w + off; off = (off + n + 255) & ~(size_t)255; return q; };

  uint4*  Ef = (uint4*)alloc((size_t)2048 * 1024);   // 2 MB (f16 frags)
  uint4*  Eb = (uint4*)alloc((size_t)2048 * 1024);   // 2 MB
  double* OA = (double*)alloc(NR * 8);
  double* OB = (double*)alloc(NR * 8);
  double* eLf = (double*)alloc(NSEG * 8);
  double* gLf = (double*)alloc(NSEG * 8);
  double* eLb = (double*)alloc(NSEG * 8);
  double* gLb = (double*)alloc(NSEG * 8);
  double* CA = (double*)alloc(NSEG * 8);
  double* CB = (double*)alloc(NSEG * 8);
  double* Zd = (double*)alloc(256);
  float*  qrows = (float*)alloc((size_t)NR * CC * 4);   // 32 MB
  const int useQ = (off <= ws_size) ? 1 : 0;

  if (!useQ)
    (void)hipMemsetAsync(out, 0, (size_t)NR * CC * 4, stream);
  crf_pack<<<dim3(1024), dim3(256), 0, stream>>>(T, Ef, Eb);
  crf_seg<<<dim3(NBLK), dim3(TPB), 0, stream>>>(scores, Ef, Eb, out,
                                                qrows, OA, OB, eLf, gLf, eLb,
                                                gLb, useQ);
  crf_stitch<<<dim3(1), dim3(128), 0, stream>>>(eLf, gLf, eLb, gLb, CA, CB, Zd);
  crf_combine<<<dim3(8192), dim3(256), 0, stream>>>(out, qrows, OA, OB, CA, CB,
                                                    Zd, useQ);
}